// Round 7
// baseline (432.946 us; speedup 1.0000x reference)
//
#include <hip/hip_runtime.h>
#include <stdint.h>

// ===========================================================================
// AnchorDataGenerator (Faster R-CNN anchor target layer), MI355X / gfx950
// Round 7: 2 launches; no histograms in the main pass.
//  - k_pre: zero 8 ctrl words + windowed per-gt max IoU (512 blocks).
//  - k_main (576 blocks x 256 thr, 4 rows/thread): IoU loop (R6 compacted-gt
//    form), writes adj + DEFAULT outputs (lab=2.0, wts=0), pushes candidates
//    (all FG; BG with mantissa < 2^15) via wave-aggregated atomics, counts
//    totals, writes labm (fallback insurance). Last-arriving block selects
//    the K=min(total,128) smallest (mantissa,idx) keys per class from the
//    candidate lists (LDS hist + exact boundary rank) and overwrites the
//    <=256 kept positions (cross-block overwrite validated R4/R5).
//    Exact fallback (2-pass labm scan) if candidate invariants fail.
// All IoU math bit-exact vs reference (contract off, IEEE div, same order).
// ===========================================================================

#define NUM_A 9
#define HW 65536
#define N_ANCH 589824
#define NG 64
#define CAPK 128u
#define CAND_CAP 4096
#define NBLK_MAIN 576
#define T_BG 32768u            // push BG candidate iff mantissa < 2^15

#define LAB_BG 0u
#define LAB_FG 1u
#define LAB_IGN 2u

// workspace layout (u32 units); total 606728 u32 ~= 2.43 MB
#define OFF_GMAX8 0                        // 64 gts x 8 slices
#define OFF_CNTF  512
#define OFF_CNTB  513
#define OFF_TOTBG 514
#define OFF_DONE  515
#define OFF_CANDF 520                      // byte 2080, 8B aligned; u64 keys
#define OFF_CANDB (OFF_CANDF + 2*CAND_CAP) // 8712
#define OFF_LABM  (OFF_CANDB + 2*CAND_CAP) // 16904

__constant__ float BA[NUM_A][4] = {
  { -84.f,  -40.f,  99.f,  55.f}, {-176.f,  -88.f, 191.f, 103.f},
  {-360.f, -184.f, 375.f, 199.f}, { -56.f,  -56.f,  71.f,  71.f},
  {-120.f, -120.f, 135.f, 135.f}, {-248.f, -248.f, 263.f, 263.f},
  { -36.f,  -80.f,  51.f,  95.f}, { -80.f, -168.f,  95.f, 183.f},
  {-168.f, -344.f, 183.f, 359.f}};

__host__ __device__ static inline void tf2x32(uint32_t k0, uint32_t k1,
                                              uint32_t x0, uint32_t x1,
                                              uint32_t* o0, uint32_t* o1) {
  const uint32_t ks2 = k0 ^ k1 ^ 0x1BD11BDAu;
#define TF_R(r) { x0 += x1; x1 = (x1 << (r)) | (x1 >> (32 - (r))); x1 ^= x0; }
  x0 += k0; x1 += k1;
  TF_R(13) TF_R(15) TF_R(26) TF_R(6)
  x0 += k1;  x1 += ks2 + 1u;
  TF_R(17) TF_R(29) TF_R(16) TF_R(24)
  x0 += ks2; x1 += k0 + 2u;
  TF_R(13) TF_R(15) TF_R(26) TF_R(6)
  x0 += k0;  x1 += k1 + 3u;
  TF_R(17) TF_R(29) TF_R(16) TF_R(24)
  x0 += k1;  x1 += ks2 + 4u;
  TF_R(13) TF_R(15) TF_R(26) TF_R(6)
  x0 += ks2; x1 += k0 + 5u;
#undef TF_R
  *o0 = x0; *o1 = x1;
}

__device__ static inline uint32_t mant_of(uint32_t k0, uint32_t k1, uint32_t n) {
  uint32_t o0, o1;
  tf2x32(k0, k1, 0u, n, &o0, &o1);   // partitionable: counter = (hi=0, lo=n)
  return (o0 ^ o1) >> 9;             // 23-bit mantissa
}

__device__ static inline uint32_t agload(const uint32_t* p) {
  return __hip_atomic_load(p, __ATOMIC_RELAXED, __HIP_MEMORY_SCOPE_AGENT);
}
__device__ static inline uint64_t agload64(const uint64_t* p) {
  return __hip_atomic_load(p, __ATOMIC_RELAXED, __HIP_MEMORY_SCOPE_AGENT);
}
__device__ static inline void agstore(uint32_t* p, uint32_t v) {
  __hip_atomic_store(p, v, __ATOMIC_RELAXED, __HIP_MEMORY_SCOPE_AGENT);
}
__device__ static inline void agstore64(uint64_t* p, uint64_t v) {
  __hip_atomic_store(p, v, __ATOMIC_RELAXED, __HIP_MEMORY_SCOPE_AGENT);
}

__device__ static inline void write_kept(int cls, uint32_t n, float inv,
                                         float* __restrict__ out_lab,
                                         float* __restrict__ out_wts) {
  uint32_t aa = n % 9u, hw = n / 9u;
  uint32_t t = aa * HW + hw;
  if (cls == 0) {
    out_lab[t] = 1.0f;
    #pragma unroll
    for (int j = 0; j < 4; j++) out_wts[(aa * 4 + j) * HW + hw] = inv;
  } else {
    out_lab[t] = 0.0f;
  }
}

// IoU in the reference's exact fp32 op order (contraction OFF).
__device__ static inline float iou1(float a0, float a1, float a2, float a3,
                                    float aarea, float g0, float g1, float g2,
                                    float g3, float garea) {
  #pragma clang fp contract(off)
  float ix1 = fmaxf(a0, g0);
  float iy1 = fmaxf(a1, g1);
  float ix2 = fminf(a2, g2);
  float iy2 = fminf(a3, g3);
  float iw = ix2 - ix1 + 1.0f;
  float ih = iy2 - iy1 + 1.0f;
  float inter = (iw > 0.0f && ih > 0.0f) ? iw * ih : 0.0f;
  float den = aarea + garea - inter;
  return inter / den;                  // IEEE-rounded div
}

// ---- k_pre: zero ctrl words + per-gt windowed max IoU (8 slices/gt) -------
__global__ __launch_bounds__(256) void k_pre(const float* __restrict__ gt,
                                             const int* __restrict__ imw_p,
                                             const int* __restrict__ imh_p,
                                             uint32_t* __restrict__ ws) {
  #pragma clang fp contract(off)
  int tid = threadIdx.x;
  int b = blockIdx.x;
  if (b == 0 && tid < 8) ws[512 + tid] = 0u;   // CNTF/CNTB/TOTBG/DONE + spare

  int g = b >> 3, sl = b & 7;
  float g0 = gt[g*4+0], g1 = gt[g*4+1], g2 = gt[g*4+2], g3 = gt[g*4+3];
  float gw = g2 - g0 + 1.0f, gh = g3 - g1 + 1.0f;
  float ga = (gw > 0.0f && gh > 0.0f) ? gw * gh : 0.0f;
  float imw = (float)imw_p[0], imh = (float)imh_p[0];

  float mx = 0.0f;   // g_max >= 0 always (some valid anchor exists)
  for (int a = 0; a < NUM_A; a++) {
    float b0 = BA[a][0], b1 = BA[a][1], b2 = BA[a][2], b3 = BA[a][3];
    int wlo = max(0,   (int)floorf((g0 - 1.0f - b2) * 0.0625f));
    int whi = min(255, (int)ceilf ((g2 + 1.0f - b0) * 0.0625f));
    int hlo = max(0,   (int)floorf((g1 - 1.0f - b3) * 0.0625f));
    int hhi = min(255, (int)ceilf ((g3 + 1.0f - b1) * 0.0625f));
    int wx = whi - wlo + 1, wy = hhi - hlo + 1;
    if (wx <= 0 || wy <= 0) continue;
    int tot = wx * wy;
    for (int idx = sl * 256 + tid; idx < tot; idx += 2048) {
      int h = hlo + idx / wx, w = wlo + idx % wx;
      float sx = (float)(w << 4), sy = (float)(h << 4);
      float x1 = b0 + sx, y1 = b1 + sy, x2 = b2 + sx, y2 = b3 + sy;
      float aw = x2 - x1 + 1.0f, ah = y2 - y1 + 1.0f;
      float aarea = aw * ah;
      bool vld = (x1 >= 0.0f) && (y1 >= 0.0f) && (x2 < imw) && (y2 < imh);
      float o = iou1(x1, y1, x2, y2, aarea, g0, g1, g2, g3, ga);
      if (vld) mx = fmaxf(mx, o);
    }
  }
  #pragma unroll
  for (int s = 32; s >= 1; s >>= 1) mx = fmaxf(mx, __shfl_xor(mx, s, 64));
  __shared__ float wmax[4];
  if ((tid & 63) == 0) wmax[tid >> 6] = mx;
  __syncthreads();
  if (tid == 0) {
    float m = fmaxf(fmaxf(wmax[0], wmax[1]), fmaxf(wmax[2], wmax[3]));
    ws[OFF_GMAX8 + g * 8 + sl] = __float_as_uint(m);
  }
}

// ---- k_main: everything else in one dispatch ------------------------------
__global__ __launch_bounds__(256) void k_main(const float* __restrict__ gt,
                                              const int* __restrict__ imw_p,
                                              const int* __restrict__ imh_p,
                                              float* __restrict__ out_lab,
                                              float* __restrict__ out_adj,
                                              float* __restrict__ out_wts,
                                              uint32_t* __restrict__ ws,
                                              uint32_t kf0, uint32_t kf1,
                                              uint32_t kb0, uint32_t kb1) {
  #pragma clang fp contract(off)
  __shared__ float4 sgt4[NG];               // original-indexed (epilogue)
  __shared__ float4 cg4[NG];                // compacted boxes
  __shared__ float2 cgam[NG];               // compacted (g_area, g_max)
  __shared__ uint32_t crow[NG];             // (rowmask<<8) | original g
  __shared__ int scnt, sAnyZero, sLast;
  __shared__ uint32_t sTotBG, sbf, sneed, sBcnt;
  __shared__ uint32_t sscan[256];
  __shared__ uint32_t shist[2048];          // 8 KB (tail only)
  __shared__ uint64_t scand[CAND_CAP];      // 32 KB (tail only)
  int tid = threadIdx.x;

  int b = blockIdx.x;
  int a = b >> 6, hb = (b & 63) << 2;       // anchor type, 4 rows hb..hb+3
  float BA0 = BA[a][0], BA1 = BA[a][1], BA2 = BA[a][2], BA3 = BA[a][3];

  if (tid == 0) { sTotBG = 0u; }
  if (tid < NG) {                           // wave 0: load + compact gts
    int g = tid;
    const float4 g4 = ((const float4*)gt)[g];
    sgt4[g] = g4;
    float gw = g4.z - g4.x + 1.0f, gh = g4.w - g4.y + 1.0f;
    float ga = (gw > 0.0f && gh > 0.0f) ? gw * gh : 0.0f;
    uint4 q0 = *(const uint4*)&ws[OFF_GMAX8 + g * 8];
    uint4 q1 = *(const uint4*)&ws[OFF_GMAX8 + g * 8 + 4];
    uint32_t mm = max(max(max(q0.x, q0.y), max(q0.z, q0.w)),
                      max(max(q1.x, q1.y), max(q1.z, q1.w)));
    uint32_t rb = 0u;
    #pragma unroll
    for (int r = 0; r < 4; r++) {
      float sy = (float)((hb + r) << 4);
      float ihp = fminf(BA3 + sy, g4.w) - fmaxf(BA1 + sy, g4.y) + 1.0f;
      if (ihp > 0.0f) rb |= (1u << r);
    }
    unsigned long long zb = __ballot(mm == 0u);
    bool pred = (rb != 0u);
    unsigned long long mk = __ballot(pred);
    int idx = __popcll(mk & ((1ull << g) - 1ull));
    if (pred) {
      cg4[idx] = g4;
      cgam[idx] = make_float2(ga, __uint_as_float(mm));
      crow[idx] = (rb << 8) | (uint32_t)g;
    }
    if (g == 0) {
      scnt = __popcll(mk);
      sAnyZero = (zb != 0ull) ? 1 : 0;      // degenerate g_max == 0
    }
  }
  __syncthreads();

  float imw = (float)imw_p[0], imh = (float)imh_p[0];
  int w = tid;
  float sx = (float)(w << 4);
  float A0 = BA0 + sx, A2 = BA2 + sx;
  float aw = A2 - A0 + 1.0f;
  float A1v[4], A3v[4];
  #pragma unroll
  for (int r = 0; r < 4; r++) {
    float sy = (float)((hb + r) << 4);
    A1v[r] = BA1 + sy; A3v[r] = BA3 + sy;
  }
  float ah = A3v[0] - A1v[0] + 1.0f;
  float aarea = aw * ah;                    // exact ints -> bit-exact
  bool xv = (A0 >= 0.0f) && (A2 < imw);

  int cnt = scnt;
  float amaxv[4] = {0.f, 0.f, 0.f, 0.f};
  int bgv[4] = {0, 0, 0, 0};
  uint32_t afv = 0u;
  for (int i = 0; i < cnt; i++) {           // ascending g -> first-max argmax
    float4 g4 = cg4[i];
    float iw = fminf(A2, g4.z) - fmaxf(A0, g4.x) + 1.0f;
    if (!__any(iw > 0.0f)) continue;
    float2 gam = cgam[i];
    uint32_t rbg = crow[i];
    if (iw > 0.0f) {
      int g = (int)(rbg & 0xFFu);
      uint32_t rb = rbg >> 8;
      float base = aarea + gam.x;
      float gm = gam.y;
      #pragma unroll
      for (int r = 0; r < 4; r++) {
        if ((rb >> r) & 1u) {               // row overlaps in y (ih>0)
          float ih = fminf(A3v[r], g4.w) - fmaxf(A1v[r], g4.y) + 1.0f;
          float inter = iw * ih;
          float o = inter / (base - inter); // IEEE
          if (o > amaxv[r]) { amaxv[r] = o; bgv[r] = g; }
          if (o == gm) afv |= (1u << r);
        }
      }
    }
  }

  bool anyZ = (sAnyZero != 0);
  uint64_t* candf = (uint64_t*)(ws + OFF_CANDF);
  uint64_t* candb = (uint64_t*)(ws + OFF_CANDB);
  uint32_t lane = (uint32_t)(tid & 63);
  unsigned long long below = (1ull << lane) - 1ull;
  uint32_t bgc = 0u;

  #pragma unroll
  for (int r = 0; r < 4; r++) {
    int hw = (hb + r) * 256 + w;
    bool valid = xv && (A1v[r] >= 0.0f) && (A3v[r] < imh);
    float amax = amaxv[r];
    bool anyfg = (((afv >> r) & 1u) || anyZ) && valid;
    uint32_t lab;
    if (!valid)                       lab = LAB_IGN;
    else if (anyfg || amax >= 0.7f)   lab = LAB_FG;
    else if (amax < 0.3f)             lab = LAB_BG;
    else                              lab = LAB_IGN;

    float adj0 = 0.f, adj1 = 0.f, adj2 = 0.f, adj3 = 0.f;
    if (valid) {
      float4 G = sgt4[bgv[r]];
      float ax = (A2 + A0) * 0.5f, ay = (A3v[r] + A1v[r]) * 0.5f;
      float gwm = G.z - G.x + 1.0f, ghm = G.w - G.y + 1.0f;
      float gx = (G.z + G.x) * 0.5f, gy = (G.w + G.y) * 0.5f;
      adj0 = (gx - ax) / aw;
      adj1 = (gy - ay) / ah;
      adj2 = logf(gwm / aw);
      adj3 = logf(ghm / ah);
    }
    int c4 = a * 4;
    out_adj[(c4 + 0) * HW + hw] = adj0;
    out_adj[(c4 + 1) * HW + hw] = adj1;
    out_adj[(c4 + 2) * HW + hw] = adj2;
    out_adj[(c4 + 3) * HW + hw] = adj3;
    // defaults: only the <=256 kept anchors get overwritten by the tail
    out_lab[a * HW + hw] = 2.0f;
    out_wts[(c4 + 0) * HW + hw] = 0.0f;
    out_wts[(c4 + 1) * HW + hw] = 0.0f;
    out_wts[(c4 + 2) * HW + hw] = 0.0f;
    out_wts[(c4 + 3) * HW + hw] = 0.0f;

    uint32_t m = 0u;
    uint32_t n = (uint32_t)(hw * 9 + a);    // original anchor index (tie-break)
    if (lab != LAB_IGN) {
      uint32_t kk0 = (lab == LAB_FG) ? kf0 : kb0;
      uint32_t kk1 = (lab == LAB_FG) ? kf1 : kb1;
      m = mant_of(kk0, kk1, n);
    }
    agstore(&ws[OFF_LABM + a * HW + hw], (lab << 24) | m);
    bgc += (lab == LAB_BG) ? 1u : 0u;

    // wave-aggregated candidate pushes
    bool pushf = (lab == LAB_FG);
    bool pushb = (lab == LAB_BG) && (m < T_BG);
    uint64_t key = ((uint64_t)m << 20) | (uint64_t)n;
    unsigned long long mkf = __ballot(pushf);
    if (mkf) {
      uint32_t c = (uint32_t)__popcll(mkf);
      int leader = __ffsll(mkf) - 1;
      uint32_t base = 0;
      if ((int)lane == leader) base = atomicAdd(&ws[OFF_CNTF], c);
      base = (uint32_t)__shfl((int)base, leader, 64);
      if (pushf) {
        uint32_t idx = base + (uint32_t)__popcll(mkf & below);
        if (idx < CAND_CAP) agstore64(&candf[idx], key);
      }
    }
    unsigned long long mkb = __ballot(pushb);
    if (mkb) {
      uint32_t c = (uint32_t)__popcll(mkb);
      int leader = __ffsll(mkb) - 1;
      uint32_t base = 0;
      if ((int)lane == leader) base = atomicAdd(&ws[OFF_CNTB], c);
      base = (uint32_t)__shfl((int)base, leader, 64);
      if (pushb) {
        uint32_t idx = base + (uint32_t)__popcll(mkb & below);
        if (idx < CAND_CAP) agstore64(&candb[idx], key);
      }
    }
  }

  // block BG total -> global; arrive
  #pragma unroll
  for (int s2 = 32; s2 >= 1; s2 >>= 1)
    bgc += (uint32_t)__shfl_xor((int)bgc, s2, 64);
  if ((tid & 63) == 0) atomicAdd(&sTotBG, bgc);
  __syncthreads();
  if (tid == 0) {
    atomicAdd(&ws[OFF_TOTBG], sTotBG);
    uint32_t prev = __hip_atomic_fetch_add(&ws[OFF_DONE], 1u,
                                           __ATOMIC_ACQ_REL,
                                           __HIP_MEMORY_SCOPE_AGENT);
    sLast = (prev == NBLK_MAIN - 1u) ? 1 : 0;
  }
  __syncthreads();

  if (sLast) {
    uint32_t cntF = agload(&ws[OFF_CNTF]);
    uint32_t cntB = agload(&ws[OFF_CNTB]);
    uint32_t totB = agload(&ws[OFF_TOTBG]);
    uint32_t Kf = cntF < CAPK ? cntF : CAPK;
    uint32_t Kb = totB < CAPK ? totB : CAPK;
    float inv = 1.0f / (float)(Kf + Kb);     // 1/num_ni
    for (int cls = 0; cls < 2; cls++) {
      uint32_t K = cls ? Kb : Kf;
      uint32_t C = cls ? cntB : cntF;
      uint32_t clsLab = cls ? LAB_BG : LAB_FG;
      bool fast = (C <= CAND_CAP) && (C >= K);  // stored-complete & covers K
      for (uint32_t i = tid; i < 2048; i += 256) shist[i] = 0u;
      if (tid == 0) { sbf = 0u; sneed = 0u; sBcnt = 0u; }
      __syncthreads();
      if (fast) {
        const uint64_t* gc = cls ? candb : candf;
        for (uint32_t i = tid; i < C; i += 256) {
          uint64_t k = agload64(&gc[i]);
          scand[i] = k;
          atomicAdd(&shist[(uint32_t)(k >> 32)], 1u);  // bin = m >> 12
        }
      } else {
        for (uint32_t t2 = tid; t2 < N_ANCH; t2 += 256) {
          uint32_t lm = agload(&ws[OFF_LABM + t2]);
          if ((lm >> 24) == clsLab)
            atomicAdd(&shist[(lm & 0x7FFFFFu) >> 12], 1u);
        }
      }
      __syncthreads();
      // block scan of 2048 bins (8/thread) -> boundary bin for K smallest
      uint32_t loc[8], s = 0;
      #pragma unroll
      for (int j = 0; j < 8; j++) { loc[j] = shist[tid * 8 + j]; s += loc[j]; }
      sscan[tid] = s;
      __syncthreads();
      for (int off = 1; off < 256; off <<= 1) {
        uint32_t v = (tid >= off) ? sscan[tid - off] : 0u;
        __syncthreads();
        sscan[tid] += v;
        __syncthreads();
      }
      if (K > 0u) {
        uint32_t myC = sscan[tid], pvC = (tid == 0) ? 0u : sscan[tid - 1];
        if (myC >= K && pvC < K) {          // exactly one thread
          uint32_t cum = pvC; uint32_t bb2 = tid * 8;
          for (int j = 0; j < 8; j++) {
            if (cum + loc[j] >= K) { bb2 = tid * 8 + j; break; }
            cum += loc[j];
          }
          sbf = bb2 + 1u;                   // +1 so 0 == "keep nothing"
          sneed = K - cum;
        }
      }
      __syncthreads();
      uint32_t bfp1 = sbf, need = sneed;
      if (bfp1 > 0u) {
        uint32_t bf = bfp1 - 1u;
        if (fast) {
          for (uint32_t i = tid; i < C; i += 256) {
            uint64_t k = scand[i];
            uint32_t bin = (uint32_t)(k >> 32);
            bool keep = false;
            if (bin < bf) keep = true;
            else if (bin == bf) {
              uint32_t r = 0;
              for (uint32_t j = 0; j < C; j++) {
                uint64_t o = scand[j];
                r += ((uint32_t)(o >> 32) == bf && o < k) ? 1u : 0u;
              }
              keep = (r < need);
            }
            if (keep)
              write_kept(cls, (uint32_t)(k & 0xFFFFFu), inv, out_lab, out_wts);
          }
        } else {
          // exact fallback: direct-keep below boundary; rank boundary bin
          for (uint32_t t2 = tid; t2 < N_ANCH; t2 += 256) {
            uint32_t lm = agload(&ws[OFF_LABM + t2]);
            if ((lm >> 24) != clsLab) continue;
            uint32_t m = lm & 0x7FFFFFu;
            uint32_t bin = m >> 12;
            if (bin > bf) continue;
            uint32_t n = (uint32_t)((t2 & 65535) * 9 + (t2 >> 16));
            if (bin < bf) {
              write_kept(cls, n, inv, out_lab, out_wts);
            } else {
              uint32_t idx = atomicAdd(&sBcnt, 1u);
              if (idx < CAND_CAP)
                scand[idx] = ((uint64_t)m << 20) | (uint64_t)n;
            }
          }
          __syncthreads();
          uint32_t Cb = sBcnt < CAND_CAP ? sBcnt : CAND_CAP;
          for (uint32_t i = tid; i < Cb; i += 256) {
            uint64_t k = scand[i];
            uint32_t r = 0;
            for (uint32_t j = 0; j < Cb; j++) r += (scand[j] < k) ? 1u : 0u;
            if (r < need)
              write_kept(cls, (uint32_t)(k & 0xFFFFFu), inv, out_lab, out_wts);
          }
        }
      }
      __syncthreads();
    }
  }
}

extern "C" void kernel_launch(void* const* d_in, const int* in_sizes, int n_in,
                              void* d_out, int out_size, void* d_ws,
                              size_t ws_size, hipStream_t stream) {
  const float* gt  = (const float*)d_in[1];
  const int*   imw = (const int*)d_in[2];
  const int*   imh = (const int*)d_in[3];
  float* out      = (float*)d_out;
  float* out_lab  = out;                   // 589824
  float* out_adj  = out + N_ANCH;          // 4*589824
  float* out_wts  = out + 5 * N_ANCH;      // 4*589824
  uint32_t* ws = (uint32_t*)d_ws;          // ~2.43 MB used

  uint32_t kf0, kf1, kb0, kb1;
  tf2x32(0u, 42u, 0u, 0u, &kf0, &kf1);
  tf2x32(0u, 42u, 0u, 1u, &kb0, &kb1);

  hipLaunchKernelGGL(k_pre, dim3(NG * 8), dim3(256), 0, stream, gt, imw, imh,
                     ws);
  hipLaunchKernelGGL(k_main, dim3(NBLK_MAIN), dim3(256), 0, stream, gt, imw,
                     imh, out_lab, out_adj, out_wts, ws, kf0, kf1, kb0, kb1);
}

// Round 8
// 121.797 us; speedup vs baseline: 3.5547x; 3.5547x over previous
//
#include <hip/hip_runtime.h>
#include <stdint.h>

// ===========================================================================
// AnchorDataGenerator (Faster R-CNN anchor target layer), MI355X / gfx950
// Round 8: R7 structure (2 launches), FG candidate capacity fixed (R7's 458us
// was the exact-fallback triggering: cntF > 4096 since FG = ALL anchors with
// IoU>=0.7, ~5-10k for 64 large gts).
//  - k_pre: zero ctrl words + windowed per-gt max IoU (512 blocks).
//  - k_main (576 blocks x 256 thr): IoU pass, defaults (lab=2, wts=0) + adj,
//    push ALL FG (cap 16384) and BG with mantissa<2^15 (cap 4096) to global
//    lists via wave-aggregated atomics; byte labels for fallback insurance.
//    Last-arriving block (ACQ_REL done-counter): per class build 2048-bin
//    hist FROM THE GLOBAL LIST, scan for boundary bin, direct-keep below it,
//    stage boundary-bin candidates in LDS and rank exactly; overwrites the
//    <=256 kept output positions. Exact byte-label fallback if caps exceeded.
// All IoU math bit-exact vs reference (contract off, IEEE div, same order).
// ===========================================================================

#define NUM_A 9
#define HW 65536
#define N_ANCH 589824
#define NG 64
#define CAPK 128u
#define CANDF_CAP 16384
#define CANDB_CAP 4096
#define BCAP 3072
#define NBLK_MAIN 576
#define T_BG 32768u            // push BG candidate iff mantissa < 2^15

#define LAB_BG 0u
#define LAB_FG 1u
#define LAB_IGN 2u

// workspace layout (u32 units); total 188936 u32 ~= 0.76 MB
#define OFF_GMAX8 0                        // 64 gts x 8 slices
#define OFF_CNTF  512
#define OFF_CNTB  513
#define OFF_TOTBG 514
#define OFF_DONE  515
#define OFF_CANDF 520                      // u64 x 16384
#define OFF_CANDB (OFF_CANDF + 2*CANDF_CAP)   // 33288, u64 x 4096
#define OFF_LABB  (OFF_CANDB + 2*CANDB_CAP)   // 41480, byte labels [N_ANCH]

__constant__ float BA[NUM_A][4] = {
  { -84.f,  -40.f,  99.f,  55.f}, {-176.f,  -88.f, 191.f, 103.f},
  {-360.f, -184.f, 375.f, 199.f}, { -56.f,  -56.f,  71.f,  71.f},
  {-120.f, -120.f, 135.f, 135.f}, {-248.f, -248.f, 263.f, 263.f},
  { -36.f,  -80.f,  51.f,  95.f}, { -80.f, -168.f,  95.f, 183.f},
  {-168.f, -344.f, 183.f, 359.f}};

__host__ __device__ static inline void tf2x32(uint32_t k0, uint32_t k1,
                                              uint32_t x0, uint32_t x1,
                                              uint32_t* o0, uint32_t* o1) {
  const uint32_t ks2 = k0 ^ k1 ^ 0x1BD11BDAu;
#define TF_R(r) { x0 += x1; x1 = (x1 << (r)) | (x1 >> (32 - (r))); x1 ^= x0; }
  x0 += k0; x1 += k1;
  TF_R(13) TF_R(15) TF_R(26) TF_R(6)
  x0 += k1;  x1 += ks2 + 1u;
  TF_R(17) TF_R(29) TF_R(16) TF_R(24)
  x0 += ks2; x1 += k0 + 2u;
  TF_R(13) TF_R(15) TF_R(26) TF_R(6)
  x0 += k0;  x1 += k1 + 3u;
  TF_R(17) TF_R(29) TF_R(16) TF_R(24)
  x0 += k1;  x1 += ks2 + 4u;
  TF_R(13) TF_R(15) TF_R(26) TF_R(6)
  x0 += ks2; x1 += k0 + 5u;
#undef TF_R
  *o0 = x0; *o1 = x1;
}

__device__ static inline uint32_t mant_of(uint32_t k0, uint32_t k1, uint32_t n) {
  uint32_t o0, o1;
  tf2x32(k0, k1, 0u, n, &o0, &o1);   // partitionable: counter = (hi=0, lo=n)
  return (o0 ^ o1) >> 9;             // 23-bit mantissa
}

__device__ static inline uint64_t agload64(const uint64_t* p) {
  return __hip_atomic_load(p, __ATOMIC_RELAXED, __HIP_MEMORY_SCOPE_AGENT);
}
__device__ static inline void agstore64(uint64_t* p, uint64_t v) {
  __hip_atomic_store(p, v, __ATOMIC_RELAXED, __HIP_MEMORY_SCOPE_AGENT);
}

__device__ static inline void write_kept(int cls, uint32_t n, float inv,
                                         float* __restrict__ out_lab,
                                         float* __restrict__ out_wts) {
  uint32_t aa = n % 9u, hw = n / 9u;
  uint32_t t = aa * HW + hw;
  if (cls == 0) {
    out_lab[t] = 1.0f;
    #pragma unroll
    for (int j = 0; j < 4; j++) out_wts[(aa * 4 + j) * HW + hw] = inv;
  } else {
    out_lab[t] = 0.0f;
  }
}

// IoU in the reference's exact fp32 op order (contraction OFF).
__device__ static inline float iou1(float a0, float a1, float a2, float a3,
                                    float aarea, float g0, float g1, float g2,
                                    float g3, float garea) {
  #pragma clang fp contract(off)
  float ix1 = fmaxf(a0, g0);
  float iy1 = fmaxf(a1, g1);
  float ix2 = fminf(a2, g2);
  float iy2 = fminf(a3, g3);
  float iw = ix2 - ix1 + 1.0f;
  float ih = iy2 - iy1 + 1.0f;
  float inter = (iw > 0.0f && ih > 0.0f) ? iw * ih : 0.0f;
  float den = aarea + garea - inter;
  return inter / den;                  // IEEE-rounded div
}

// ---- k_pre: zero ctrl words + per-gt windowed max IoU (8 slices/gt) -------
__global__ __launch_bounds__(256) void k_pre(const float* __restrict__ gt,
                                             const int* __restrict__ imw_p,
                                             const int* __restrict__ imh_p,
                                             uint32_t* __restrict__ ws) {
  #pragma clang fp contract(off)
  int tid = threadIdx.x;
  int b = blockIdx.x;
  if (b == 0 && tid < 8) ws[512 + tid] = 0u;   // CNTF/CNTB/TOTBG/DONE + spare

  int g = b >> 3, sl = b & 7;
  float g0 = gt[g*4+0], g1 = gt[g*4+1], g2 = gt[g*4+2], g3 = gt[g*4+3];
  float gw = g2 - g0 + 1.0f, gh = g3 - g1 + 1.0f;
  float ga = (gw > 0.0f && gh > 0.0f) ? gw * gh : 0.0f;
  float imw = (float)imw_p[0], imh = (float)imh_p[0];

  float mx = 0.0f;   // g_max >= 0 always (some valid anchor exists)
  for (int a = 0; a < NUM_A; a++) {
    float b0 = BA[a][0], b1 = BA[a][1], b2 = BA[a][2], b3 = BA[a][3];
    int wlo = max(0,   (int)floorf((g0 - 1.0f - b2) * 0.0625f));
    int whi = min(255, (int)ceilf ((g2 + 1.0f - b0) * 0.0625f));
    int hlo = max(0,   (int)floorf((g1 - 1.0f - b3) * 0.0625f));
    int hhi = min(255, (int)ceilf ((g3 + 1.0f - b1) * 0.0625f));
    int wx = whi - wlo + 1, wy = hhi - hlo + 1;
    if (wx <= 0 || wy <= 0) continue;
    int tot = wx * wy;
    for (int idx = sl * 256 + tid; idx < tot; idx += 2048) {
      int h = hlo + idx / wx, w = wlo + idx % wx;
      float sx = (float)(w << 4), sy = (float)(h << 4);
      float x1 = b0 + sx, y1 = b1 + sy, x2 = b2 + sx, y2 = b3 + sy;
      float aw = x2 - x1 + 1.0f, ah = y2 - y1 + 1.0f;
      float aarea = aw * ah;
      bool vld = (x1 >= 0.0f) && (y1 >= 0.0f) && (x2 < imw) && (y2 < imh);
      float o = iou1(x1, y1, x2, y2, aarea, g0, g1, g2, g3, ga);
      if (vld) mx = fmaxf(mx, o);
    }
  }
  #pragma unroll
  for (int s = 32; s >= 1; s >>= 1) mx = fmaxf(mx, __shfl_xor(mx, s, 64));
  __shared__ float wmax[4];
  if ((tid & 63) == 0) wmax[tid >> 6] = mx;
  __syncthreads();
  if (tid == 0) {
    float m = fmaxf(fmaxf(wmax[0], wmax[1]), fmaxf(wmax[2], wmax[3]));
    ws[OFF_GMAX8 + g * 8 + sl] = __float_as_uint(m);
  }
}

// ---- k_main: everything else in one dispatch ------------------------------
__global__ __launch_bounds__(256) void k_main(const float* __restrict__ gt,
                                              const int* __restrict__ imw_p,
                                              const int* __restrict__ imh_p,
                                              float* __restrict__ out_lab,
                                              float* __restrict__ out_adj,
                                              float* __restrict__ out_wts,
                                              uint32_t* __restrict__ ws,
                                              uint32_t kf0, uint32_t kf1,
                                              uint32_t kb0, uint32_t kb1) {
  #pragma clang fp contract(off)
  __shared__ float4 sgt4[NG];               // original-indexed (epilogue)
  __shared__ float4 cg4[NG];                // compacted boxes
  __shared__ float2 cgam[NG];               // compacted (g_area, g_max)
  __shared__ uint32_t crow[NG];             // (rowmask<<8) | original g
  __shared__ int scnt, sAnyZero, sLast;
  __shared__ uint32_t sTotBG, sbf, sneed, sBcnt;
  __shared__ uint32_t sscan[256];
  __shared__ uint32_t shist[2048];          // 8 KB (tail only)
  __shared__ uint64_t scand[BCAP];          // 24 KB (tail only)
  int tid = threadIdx.x;

  int b = blockIdx.x;
  int a = b >> 6, hb = (b & 63) << 2;       // anchor type, 4 rows hb..hb+3
  float BA0 = BA[a][0], BA1 = BA[a][1], BA2 = BA[a][2], BA3 = BA[a][3];

  if (tid == 0) { sTotBG = 0u; }
  if (tid < NG) {                           // wave 0: load + compact gts
    int g = tid;
    const float4 g4 = ((const float4*)gt)[g];
    sgt4[g] = g4;
    float gw = g4.z - g4.x + 1.0f, gh = g4.w - g4.y + 1.0f;
    float ga = (gw > 0.0f && gh > 0.0f) ? gw * gh : 0.0f;
    uint4 q0 = *(const uint4*)&ws[OFF_GMAX8 + g * 8];
    uint4 q1 = *(const uint4*)&ws[OFF_GMAX8 + g * 8 + 4];
    uint32_t mm = max(max(max(q0.x, q0.y), max(q0.z, q0.w)),
                      max(max(q1.x, q1.y), max(q1.z, q1.w)));
    uint32_t rb = 0u;
    #pragma unroll
    for (int r = 0; r < 4; r++) {
      float sy = (float)((hb + r) << 4);
      float ihp = fminf(BA3 + sy, g4.w) - fmaxf(BA1 + sy, g4.y) + 1.0f;
      if (ihp > 0.0f) rb |= (1u << r);
    }
    unsigned long long zb = __ballot(mm == 0u);
    bool pred = (rb != 0u);
    unsigned long long mk = __ballot(pred);
    int idx = __popcll(mk & ((1ull << g) - 1ull));
    if (pred) {
      cg4[idx] = g4;
      cgam[idx] = make_float2(ga, __uint_as_float(mm));
      crow[idx] = (rb << 8) | (uint32_t)g;
    }
    if (g == 0) {
      scnt = __popcll(mk);
      sAnyZero = (zb != 0ull) ? 1 : 0;      // degenerate g_max == 0
    }
  }
  __syncthreads();

  float imw = (float)imw_p[0], imh = (float)imh_p[0];
  int w = tid;
  float sx = (float)(w << 4);
  float A0 = BA0 + sx, A2 = BA2 + sx;
  float aw = A2 - A0 + 1.0f;
  float A1v[4], A3v[4];
  #pragma unroll
  for (int r = 0; r < 4; r++) {
    float sy = (float)((hb + r) << 4);
    A1v[r] = BA1 + sy; A3v[r] = BA3 + sy;
  }
  float ah = A3v[0] - A1v[0] + 1.0f;
  float aarea = aw * ah;                    // exact ints -> bit-exact
  bool xv = (A0 >= 0.0f) && (A2 < imw);

  int cnt = scnt;
  float amaxv[4] = {0.f, 0.f, 0.f, 0.f};
  int bgv[4] = {0, 0, 0, 0};
  uint32_t afv = 0u;
  for (int i = 0; i < cnt; i++) {           // ascending g -> first-max argmax
    float4 g4 = cg4[i];
    float iw = fminf(A2, g4.z) - fmaxf(A0, g4.x) + 1.0f;
    if (!__any(iw > 0.0f)) continue;
    float2 gam = cgam[i];
    uint32_t rbg = crow[i];
    if (iw > 0.0f) {
      int g = (int)(rbg & 0xFFu);
      uint32_t rb = rbg >> 8;
      float base = aarea + gam.x;
      float gm = gam.y;
      #pragma unroll
      for (int r = 0; r < 4; r++) {
        if ((rb >> r) & 1u) {               // row overlaps in y (ih>0)
          float ih = fminf(A3v[r], g4.w) - fmaxf(A1v[r], g4.y) + 1.0f;
          float inter = iw * ih;
          float o = inter / (base - inter); // IEEE
          if (o > amaxv[r]) { amaxv[r] = o; bgv[r] = g; }
          if (o == gm) afv |= (1u << r);
        }
      }
    }
  }

  bool anyZ = (sAnyZero != 0);
  uint64_t* candf = (uint64_t*)(ws + OFF_CANDF);
  uint64_t* candb = (uint64_t*)(ws + OFF_CANDB);
  uint8_t* labb = (uint8_t*)(ws + OFF_LABB);
  uint32_t lane = (uint32_t)(tid & 63);
  unsigned long long below = (1ull << lane) - 1ull;
  uint32_t bgc = 0u;

  #pragma unroll
  for (int r = 0; r < 4; r++) {
    int hw = (hb + r) * 256 + w;
    bool valid = xv && (A1v[r] >= 0.0f) && (A3v[r] < imh);
    float amax = amaxv[r];
    bool anyfg = (((afv >> r) & 1u) || anyZ) && valid;
    uint32_t lab;
    if (!valid)                       lab = LAB_IGN;
    else if (anyfg || amax >= 0.7f)   lab = LAB_FG;
    else if (amax < 0.3f)             lab = LAB_BG;
    else                              lab = LAB_IGN;

    float adj0 = 0.f, adj1 = 0.f, adj2 = 0.f, adj3 = 0.f;
    if (valid) {
      float4 G = sgt4[bgv[r]];
      float ax = (A2 + A0) * 0.5f, ay = (A3v[r] + A1v[r]) * 0.5f;
      float gwm = G.z - G.x + 1.0f, ghm = G.w - G.y + 1.0f;
      float gx = (G.z + G.x) * 0.5f, gy = (G.w + G.y) * 0.5f;
      adj0 = (gx - ax) / aw;
      adj1 = (gy - ay) / ah;
      adj2 = logf(gwm / aw);
      adj3 = logf(ghm / ah);
    }
    int c4 = a * 4;
    out_adj[(c4 + 0) * HW + hw] = adj0;
    out_adj[(c4 + 1) * HW + hw] = adj1;
    out_adj[(c4 + 2) * HW + hw] = adj2;
    out_adj[(c4 + 3) * HW + hw] = adj3;
    // defaults: only the <=256 kept anchors get overwritten by the tail
    out_lab[a * HW + hw] = 2.0f;
    out_wts[(c4 + 0) * HW + hw] = 0.0f;
    out_wts[(c4 + 1) * HW + hw] = 0.0f;
    out_wts[(c4 + 2) * HW + hw] = 0.0f;
    out_wts[(c4 + 3) * HW + hw] = 0.0f;

    uint32_t m = 0u;
    uint32_t n = (uint32_t)(hw * 9 + a);    // original anchor index (tie-break)
    if (lab != LAB_IGN) {
      uint32_t kk0 = (lab == LAB_FG) ? kf0 : kb0;
      uint32_t kk1 = (lab == LAB_FG) ? kf1 : kb1;
      m = mant_of(kk0, kk1, n);
    }
    labb[a * HW + hw] = (uint8_t)lab;       // fallback insurance
    bgc += (lab == LAB_BG) ? 1u : 0u;

    // wave-aggregated candidate pushes
    bool pushf = (lab == LAB_FG);
    bool pushb = (lab == LAB_BG) && (m < T_BG);
    uint64_t key = ((uint64_t)m << 20) | (uint64_t)n;
    unsigned long long mkf = __ballot(pushf);
    if (mkf) {
      uint32_t c = (uint32_t)__popcll(mkf);
      int leader = __ffsll(mkf) - 1;
      uint32_t base = 0;
      if ((int)lane == leader) base = atomicAdd(&ws[OFF_CNTF], c);
      base = (uint32_t)__shfl((int)base, leader, 64);
      if (pushf) {
        uint32_t idx = base + (uint32_t)__popcll(mkf & below);
        if (idx < CANDF_CAP) agstore64(&candf[idx], key);
      }
    }
    unsigned long long mkb = __ballot(pushb);
    if (mkb) {
      uint32_t c = (uint32_t)__popcll(mkb);
      int leader = __ffsll(mkb) - 1;
      uint32_t base = 0;
      if ((int)lane == leader) base = atomicAdd(&ws[OFF_CNTB], c);
      base = (uint32_t)__shfl((int)base, leader, 64);
      if (pushb) {
        uint32_t idx = base + (uint32_t)__popcll(mkb & below);
        if (idx < CANDB_CAP) agstore64(&candb[idx], key);
      }
    }
  }

  // block BG total -> global; arrive (release)
  #pragma unroll
  for (int s2 = 32; s2 >= 1; s2 >>= 1)
    bgc += (uint32_t)__shfl_xor((int)bgc, s2, 64);
  if ((tid & 63) == 0) atomicAdd(&sTotBG, bgc);
  __syncthreads();
  if (tid == 0) {
    atomicAdd(&ws[OFF_TOTBG], sTotBG);
    uint32_t prev = __hip_atomic_fetch_add(&ws[OFF_DONE], 1u,
                                           __ATOMIC_ACQ_REL,
                                           __HIP_MEMORY_SCOPE_AGENT);
    sLast = (prev == NBLK_MAIN - 1u) ? 1 : 0;
  }
  __syncthreads();
  if (!sLast) return;

  // ---------------- tail: subsample selection (last block only) ------------
  uint32_t cntF = ws[OFF_CNTF];
  uint32_t cntB = ws[OFF_CNTB];
  uint32_t totB = ws[OFF_TOTBG];
  uint32_t Kf = cntF < CAPK ? cntF : CAPK;
  uint32_t Kb = totB < CAPK ? totB : CAPK;
  float inv = 1.0f / (float)(Kf + Kb);       // 1/num_ni
  for (int cls = 0; cls < 2; cls++) {
    uint32_t K = cls ? Kb : Kf;
    uint32_t C = cls ? cntB : cntF;
    uint32_t cap = cls ? CANDB_CAP : CANDF_CAP;
    uint32_t clsLab = cls ? LAB_BG : LAB_FG;
    uint32_t ck0 = cls ? kb0 : kf0, ck1 = cls ? kb1 : kf1;
    const uint64_t* gc = cls ? candb : candf;
    bool fast = (C <= cap) && (C >= K);      // stored-complete & covers K
    for (uint32_t i = tid; i < 2048; i += 256) shist[i] = 0u;
    if (tid == 0) { sbf = 0u; sneed = 0u; sBcnt = 0u; }
    __syncthreads();
    if (fast) {
      for (uint32_t i = tid; i < C; i += 256)
        atomicAdd(&shist[(uint32_t)(agload64(&gc[i]) >> 32)], 1u); // m>>12
    } else {
      for (uint32_t t2 = tid; t2 < N_ANCH; t2 += 256) {
        if ((uint32_t)labb[t2] == clsLab) {
          uint32_t n = (uint32_t)((t2 & 65535) * 9 + (t2 >> 16));
          atomicAdd(&shist[mant_of(ck0, ck1, n) >> 12], 1u);
        }
      }
    }
    __syncthreads();
    // block scan of 2048 bins (8/thread) -> boundary bin for K smallest
    uint32_t loc[8], s = 0;
    #pragma unroll
    for (int j = 0; j < 8; j++) { loc[j] = shist[tid * 8 + j]; s += loc[j]; }
    sscan[tid] = s;
    __syncthreads();
    for (int off = 1; off < 256; off <<= 1) {
      uint32_t v = (tid >= off) ? sscan[tid - off] : 0u;
      __syncthreads();
      sscan[tid] += v;
      __syncthreads();
    }
    if (K > 0u) {
      uint32_t myC = sscan[tid], pvC = (tid == 0) ? 0u : sscan[tid - 1];
      if (myC >= K && pvC < K) {          // exactly one thread
        uint32_t cum = pvC; uint32_t bb2 = tid * 8;
        for (int j = 0; j < 8; j++) {
          if (cum + loc[j] >= K) { bb2 = tid * 8 + j; break; }
          cum += loc[j];
        }
        sbf = bb2 + 1u;                   // +1 so 0 == "keep nothing"
        sneed = K - cum;
      }
    }
    __syncthreads();
    uint32_t bfp1 = sbf, need = sneed;
    if (bfp1 > 0u) {
      uint32_t bf = bfp1 - 1u;
      if (fast) {
        // direct-keep below boundary; stage boundary bin into LDS
        for (uint32_t i = tid; i < C; i += 256) {
          uint64_t k = agload64(&gc[i]);
          uint32_t bin = (uint32_t)(k >> 32);
          if (bin < bf) {
            write_kept(cls, (uint32_t)(k & 0xFFFFFu), inv, out_lab, out_wts);
          } else if (bin == bf) {
            uint32_t idx = atomicAdd(&sBcnt, 1u);
            if (idx < BCAP) scand[idx] = k;
          }
        }
        __syncthreads();
        if (sBcnt <= BCAP) {
          uint32_t Cb = sBcnt;
          for (uint32_t i = tid; i < Cb; i += 256) {
            uint64_t k = scand[i];
            uint32_t r = 0;
            for (uint32_t j = 0; j < Cb; j++) r += (scand[j] < k) ? 1u : 0u;
            if (r < need)
              write_kept(cls, (uint32_t)(k & 0xFFFFFu), inv, out_lab, out_wts);
          }
        } else {
          // staging overflow (never expected): rank vs global list
          for (uint32_t i = tid; i < C; i += 256) {
            uint64_t k = agload64(&gc[i]);
            if ((uint32_t)(k >> 32) != bf) continue;
            uint32_t r = 0;
            for (uint32_t j = 0; j < C; j++) {
              uint64_t o = agload64(&gc[j]);
              r += ((uint32_t)(o >> 32) == bf && o < k) ? 1u : 0u;
            }
            if (r < need)
              write_kept(cls, (uint32_t)(k & 0xFFFFFu), inv, out_lab, out_wts);
          }
        }
      } else {
        // exact fallback over byte labels (insurance; never expected)
        for (uint32_t t2 = tid; t2 < N_ANCH; t2 += 256) {
          if ((uint32_t)labb[t2] != clsLab) continue;
          uint32_t n = (uint32_t)((t2 & 65535) * 9 + (t2 >> 16));
          uint32_t m = mant_of(ck0, ck1, n);
          uint32_t bin = m >> 12;
          if (bin > bf) continue;
          if (bin < bf) {
            write_kept(cls, n, inv, out_lab, out_wts);
          } else {
            uint32_t idx = atomicAdd(&sBcnt, 1u);
            if (idx < BCAP) scand[idx] = ((uint64_t)m << 20) | (uint64_t)n;
          }
        }
        __syncthreads();
        uint32_t Cb = sBcnt < BCAP ? sBcnt : BCAP;
        for (uint32_t i = tid; i < Cb; i += 256) {
          uint64_t k = scand[i];
          uint32_t r = 0;
          for (uint32_t j = 0; j < Cb; j++) r += (scand[j] < k) ? 1u : 0u;
          if (r < need)
            write_kept(cls, (uint32_t)(k & 0xFFFFFu), inv, out_lab, out_wts);
        }
      }
    }
    __syncthreads();
  }
}

extern "C" void kernel_launch(void* const* d_in, const int* in_sizes, int n_in,
                              void* d_out, int out_size, void* d_ws,
                              size_t ws_size, hipStream_t stream) {
  const float* gt  = (const float*)d_in[1];
  const int*   imw = (const int*)d_in[2];
  const int*   imh = (const int*)d_in[3];
  float* out      = (float*)d_out;
  float* out_lab  = out;                   // 589824
  float* out_adj  = out + N_ANCH;          // 4*589824
  float* out_wts  = out + 5 * N_ANCH;      // 4*589824
  uint32_t* ws = (uint32_t*)d_ws;          // ~0.76 MB used

  uint32_t kf0, kf1, kb0, kb1;
  tf2x32(0u, 42u, 0u, 0u, &kf0, &kf1);
  tf2x32(0u, 42u, 0u, 1u, &kb0, &kb1);

  hipLaunchKernelGGL(k_pre, dim3(NG * 8), dim3(256), 0, stream, gt, imw, imh,
                     ws);
  hipLaunchKernelGGL(k_main, dim3(NBLK_MAIN), dim3(256), 0, stream, gt, imw,
                     imh, out_lab, out_adj, out_wts, ws, kf0, kf1, kb0, kb1);
}